// Round 5
// baseline (306.936 us; speedup 1.0000x reference)
//
#include <hip/hip_runtime.h>
#include <hip/hip_bf16.h>

// CrossLocal: B=4, C=64, CI=32, cross 64x64 (Nc=4096), main 128x128.
// R15: attn blocks process 64 queries (two 32-q tiles) sharing every K/V
// fragment load -> L1/TA traffic halved (256->128 MB). Grid (64,4,2)x256,
// 3-stage K/V pipeline as R10. ~180 VGPR, grid-limited 2 blocks/CU (safe,
// no launch_bounds cap -- R12 lesson). BN stats fused into the small
// attn_combine kernel (NOT the MFMA kernel -- R13 cliff lesson);
// stats_kernel removed; qkv zeroes stats1; up reads fused stats.
// ws: Qb[bf16 1MB] Kb[1MB] Vt[1MB] out2[f32 4MB] stats1[128 f32]
//     pnum[f32 4MB] pden[f32 128KB]

typedef __attribute__((ext_vector_type(8))) short bf16x8;
typedef __attribute__((ext_vector_type(4))) float f32x4;
typedef __attribute__((ext_vector_type(16))) float f32x16;

#define LOG2E 1.4426950408889634f

static __device__ __forceinline__ unsigned short f2bf_bits(float x) {
    __hip_bfloat16 h = __float2bfloat16(x);
    return *(unsigned short*)&h;
}
static __device__ __forceinline__ unsigned int pk2bf(float a, float b) {
    __hip_bfloat162 h = __float22bfloat162_rn(make_float2(a, b));
    return *(unsigned int*)&h;
}

// exp2 all 16 S entries, accumulate denominator, pack to two bf16x8 A-frags.
static __device__ __forceinline__ void softmax_pack(
    const f32x16& s, float& den, bf16x8& ap1, bf16x8& ap2)
{
    float e[16];
#pragma unroll
    for (int r = 0; r < 16; ++r) e[r] = __builtin_amdgcn_exp2f(s[r]);
    den += (((e[0]+e[1])+(e[2]+e[3])) + ((e[4]+e[5])+(e[6]+e[7])))
         + (((e[8]+e[9])+(e[10]+e[11])) + ((e[12]+e[13])+(e[14]+e[15])));
    uint4 t1 = make_uint4(pk2bf(e[0],e[1]), pk2bf(e[2],e[3]),
                          pk2bf(e[4],e[5]), pk2bf(e[6],e[7]));
    uint4 t2 = make_uint4(pk2bf(e[8],e[9]), pk2bf(e[10],e[11]),
                          pk2bf(e[12],e[13]), pk2bf(e[14],e[15]));
    ap1 = *(bf16x8*)&t1; ap2 = *(bf16x8*)&t2;
}

// ---------------- Kernel 1: Q,K,V prep (R9/R10 verbatim + stats zero) --------
__global__ __launch_bounds__(256) void qkv_kernel(
    const float* __restrict__ cross, const float* __restrict__ mainf,
    const float* __restrict__ g_w,  const float* __restrict__ g_b,
    const float* __restrict__ th_w, const float* __restrict__ th_b,
    const float* __restrict__ ph_w, const float* __restrict__ ph_b,
    __hip_bfloat16* __restrict__ Qb, __hip_bfloat16* __restrict__ Kb,
    __hip_bfloat16* __restrict__ Vt, float* __restrict__ stats1)
{
    __shared__ float xs[64][128];            // 32 KB
    const int kind = blockIdx.x >> 7;        // 0=Q,1=K,2=V
    const int sub  = blockIdx.x & 127;
    const int b    = sub >> 5;
    const int n0   = (sub & 31) << 7;        // 128 pixels per block
    const int tid  = threadIdx.x;
    const float* w  = (kind == 0) ? g_w : (kind == 1) ? th_w : ph_w;
    const float* bs = (kind == 0) ? g_b : (kind == 1) ? th_b : ph_b;

    if (blockIdx.x == 0 && tid < 128) stats1[tid] = 0.f;  // BN accumulators

    if (kind < 2) {
        const float* src = cross + (((size_t)(b * 64)) << 12) + n0;
        const int jr = (tid & 31) << 2, c0 = tid >> 5;
#pragma unroll
        for (int it = 0; it < 8; ++it) {
            int c = (it << 3) | c0;
            *(float4*)&xs[c][jr] = *(const float4*)(src + ((size_t)c << 12) + jr);
        }
    } else {
        const int px = tid & 127, chh = tid >> 7;
        const int n = n0 + px;
        const int i2 = (n >> 6) << 1, j2 = (n & 63) << 1;
        const float* src = mainf + (((size_t)(b * 64)) << 14) + i2 * 128 + j2;
#pragma unroll 4
        for (int cc = 0; cc < 32; ++cc) {
            int c = (chh << 5) | cc;
            const float2 a = *(const float2*)(src + ((size_t)c << 14));
            const float2 d = *(const float2*)(src + ((size_t)c << 14) + 128);
            xs[c][px] = 0.25f * ((a.x + a.y) + (d.x + d.y));
        }
    }
    __syncthreads();

    const int px = tid & 127, cih = tid >> 7, ci0 = cih << 4;
    float acc[16];
#pragma unroll
    for (int j = 0; j < 16; ++j) acc[j] = bs[ci0 + j];
#pragma unroll 4
    for (int c = 0; c < 64; ++c) {
        float x = xs[c][px];
#pragma unroll
        for (int j = 0; j < 16; ++j)
            acc[j] = fmaf(w[((ci0 + j) << 6) + c], x, acc[j]);
    }
    const int n = n0 + px;
    const int pix = (b << 12) + n;
    if (kind < 2) {
        if (kind == 0) {
#pragma unroll
            for (int j = 0; j < 16; ++j) acc[j] *= LOG2E;
        }
        unsigned int u[8];
#pragma unroll
        for (int i = 0; i < 8; ++i)
            u[i] = (unsigned int)f2bf_bits(acc[2 * i]) |
                   ((unsigned int)f2bf_bits(acc[2 * i + 1]) << 16);
        uint4* d4 = (uint4*)(((kind == 0) ? Qb : Kb) + (size_t)pix * 32 + ci0);
        d4[0] = make_uint4(u[0], u[1], u[2], u[3]);
        d4[1] = make_uint4(u[4], u[5], u[6], u[7]);
    } else {
#pragma unroll
        for (int j = 0; j < 16; ++j)
            Vt[((size_t)((b << 5) | (ci0 + j)) << 12) + n] = __float2bfloat16(acc[j]);
    }
}

// ---------------- Kernel 2: split flash attention, 64-q blocks ----------------
// grid (64 q-pairs, 4 batch, 2 halves) x 256 thr. Wave w owns keys
// [half*2048 + w*512, +512), 16 chunks of 32 keys. Two q-tiles (A=qbase..+31,
// B=+32..63) share every K/V load. Writes pnum[tile][32q][32ci], pden[tile][32q];
// tile = ((half*4+b)<<7) | (blockIdx.x*2+T).
__global__ __launch_bounds__(256) void attn_part(
    const __hip_bfloat16* __restrict__ Qb, const __hip_bfloat16* __restrict__ Kb,
    const __hip_bfloat16* __restrict__ Vt,
    float* __restrict__ pnum, float* __restrict__ pden)
{
    __shared__ __align__(16) float redbuf[3][64][20];
    const int tid = threadIdx.x, lane = tid & 63, w = tid >> 6;
    const int q = lane & 31, h = lane >> 5;
    const int b = blockIdx.y, qbase = blockIdx.x << 6, half = blockIdx.z;
    // sigma: swap bits 2 and 3 of q (K-row permutation)
    const int sig = (q & ~12) | ((q & 4) << 1) | ((q & 8) >> 1);

    // Q B-frags for both tiles: B[k=ci][n=q] -> Qb[qbase(+32)+q][ci=8h.. (+16)]
    const __hip_bfloat16* QrowA = Qb + (((size_t)(b << 12) + qbase + q) << 5);
    const bf16x8 bq1A = *(const bf16x8*)(QrowA + 8 * h);
    const bf16x8 bq2A = *(const bf16x8*)(QrowA + 16 + 8 * h);
    const __hip_bfloat16* QrowB = QrowA + (32 << 5);
    const bf16x8 bq1B = *(const bf16x8*)(QrowB + 8 * h);
    const bf16x8 bq2B = *(const bf16x8*)(QrowB + 16 + 8 * h);

    const __hip_bfloat16* Kbb = Kb + ((size_t)(b << 12) << 5);
    const __hip_bfloat16* Vbb = Vt + ((size_t)(b << 5) << 12) + ((size_t)q << 12);
    const int kq = (half << 11) + (w << 9);
#define LDK1(k) (*(const bf16x8*)(Kbb + ((size_t)((k) + sig) << 5) + 8 * h))
#define LDK2(k) (*(const bf16x8*)(Kbb + ((size_t)((k) + sig) << 5) + 16 + 8 * h))
#define LDV1(k) (*(const bf16x8*)(Vbb + (k) + 8 * h))
#define LDV2(k) (*(const bf16x8*)(Vbb + (k) + 16 + 8 * h))

    f32x16 accA, accB;
#pragma unroll
    for (int r = 0; r < 16; ++r) { accA[r] = 0.f; accB[r] = 0.f; }
    const f32x16 z16 = accA;
    float denA = 0.f, denB = 0.f;

    bf16x8 a1c = LDK1(kq),      a2c = LDK2(kq);
    bf16x8 vb1 = LDV1(kq),      vb2 = LDV2(kq);
    bf16x8 a1n = LDK1(kq + 32), a2n = LDK2(kq + 32);
    bf16x8 vn1 = LDV1(kq + 32), vn2 = LDV2(kq + 32);
    bf16x8 apA1, apA2, apB1, apB2, vp1, vp2;

    // ---- chunk 0: S phase only, both tiles ----
    {
        f32x16 sA = __builtin_amdgcn_mfma_f32_32x32x16_bf16(a1c, bq1A, z16, 0, 0, 0);
        sA = __builtin_amdgcn_mfma_f32_32x32x16_bf16(a2c, bq2A, sA, 0, 0, 0);
        f32x16 sB = __builtin_amdgcn_mfma_f32_32x32x16_bf16(a1c, bq1B, z16, 0, 0, 0);
        sB = __builtin_amdgcn_mfma_f32_32x32x16_bf16(a2c, bq2B, sB, 0, 0, 0);
        softmax_pack(sA, denA, apA1, apA2);
        softmax_pack(sB, denB, apB1, apB2);
    }

#pragma unroll 2
    for (int ch = 1; ch < 16; ++ch) {
        const int kn = kq + ((ch + 1) & 15) * 32;   // last iter wraps in-range
        vp1 = vb1; vp2 = vb2;          // V(ch-1) for this iter's PV
        vb1 = vn1; vb2 = vn2;          // V(ch)
        a1c = a1n; a2c = a2n;          // K(ch)
        a1n = LDK1(kn); a2n = LDK2(kn);
        vn1 = LDV1(kn); vn2 = LDV2(kn);

        // S of chunk ch, both tiles (shared K frags)
        f32x16 sA = __builtin_amdgcn_mfma_f32_32x32x16_bf16(a1c, bq1A, z16, 0, 0, 0);
        sA = __builtin_amdgcn_mfma_f32_32x32x16_bf16(a2c, bq2A, sA, 0, 0, 0);
        f32x16 sB = __builtin_amdgcn_mfma_f32_32x32x16_bf16(a1c, bq1B, z16, 0, 0, 0);
        sB = __builtin_amdgcn_mfma_f32_32x32x16_bf16(a2c, bq2B, sB, 0, 0, 0);

        // PV of chunk ch-1 (ap packed last iteration, shared V frags)
        accA = __builtin_amdgcn_mfma_f32_32x32x16_bf16(apA1, vp1, accA, 0, 0, 0);
        accA = __builtin_amdgcn_mfma_f32_32x32x16_bf16(apA2, vp2, accA, 0, 0, 0);
        accB = __builtin_amdgcn_mfma_f32_32x32x16_bf16(apB1, vp1, accB, 0, 0, 0);
        accB = __builtin_amdgcn_mfma_f32_32x32x16_bf16(apB2, vp2, accB, 0, 0, 0);

        softmax_pack(sA, denA, apA1, apA2);
        softmax_pack(sB, denB, apB1, apB2);
    }
    // tail: PV of chunk 15 (V(15) sits in vb1/vb2 after last rotation)
    accA = __builtin_amdgcn_mfma_f32_32x32x16_bf16(apA1, vb1, accA, 0, 0, 0);
    accA = __builtin_amdgcn_mfma_f32_32x32x16_bf16(apA2, vb2, accA, 0, 0, 0);
    accB = __builtin_amdgcn_mfma_f32_32x32x16_bf16(apB1, vb1, accB, 0, 0, 0);
    accB = __builtin_amdgcn_mfma_f32_32x32x16_bf16(apB2, vb2, accB, 0, 0, 0);
#undef LDK1
#undef LDK2
#undef LDV1
#undef LDV2

    // den(lane) covers query q over this lane's 16 keys/chunk; other half:
    denA += __shfl_xor(denA, 32);
    denB += __shfl_xor(denB, 32);

    const int tileA = (((half << 2) | b) << 7) | (blockIdx.x << 1);

    // ---- tile A cross-wave combine + partial write ----
    if (w) {
        float* rb = &redbuf[w - 1][lane][0];
        f32x4* rb4 = (f32x4*)rb;
#pragma unroll
        for (int p = 0; p < 4; ++p) {
            f32x4 t = {accA[4*p], accA[4*p+1], accA[4*p+2], accA[4*p+3]};
            rb4[p] = t;
        }
        rb[16] = denA;
    }
    __syncthreads();
    if (w == 0) {
#pragma unroll
        for (int ww = 0; ww < 3; ++ww) {
            const float* rb = &redbuf[ww][lane][0];
            const f32x4* rb4 = (const f32x4*)rb;
#pragma unroll
            for (int p = 0; p < 4; ++p) {
                f32x4 t = rb4[p];
                accA[4*p] += t[0]; accA[4*p+1] += t[1];
                accA[4*p+2] += t[2]; accA[4*p+3] += t[3];
            }
            denA += rb[16];
        }
        // O^T C-layout: row(query)=(r&3)+8*(r>>2)+4h, col(ci)=q
        float* pn = pnum + ((size_t)tileA << 10);
#pragma unroll
        for (int r = 0; r < 16; ++r) {
            int qr = (r & 3) + 8 * (r >> 2) + 4 * h;
            pn[(qr << 5) + q] = accA[r];
        }
        if (h == 0) pden[(tileA << 5) + q] = denA;
    }
    __syncthreads();

    // ---- tile B cross-wave combine + partial write ----
    if (w) {
        float* rb = &redbuf[w - 1][lane][0];
        f32x4* rb4 = (f32x4*)rb;
#pragma unroll
        for (int p = 0; p < 4; ++p) {
            f32x4 t = {accB[4*p], accB[4*p+1], accB[4*p+2], accB[4*p+3]};
            rb4[p] = t;
        }
        rb[16] = denB;
    }
    __syncthreads();
    if (w == 0) {
#pragma unroll
        for (int ww = 0; ww < 3; ++ww) {
            const float* rb = &redbuf[ww][lane][0];
            const f32x4* rb4 = (const f32x4*)rb;
#pragma unroll
            for (int p = 0; p < 4; ++p) {
                f32x4 t = rb4[p];
                accB[4*p] += t[0]; accB[4*p+1] += t[1];
                accB[4*p+2] += t[2]; accB[4*p+3] += t[3];
            }
            denB += rb[16];
        }
        float* pn = pnum + ((size_t)(tileA | 1) << 10);
#pragma unroll
        for (int r = 0; r < 16; ++r) {
            int qr = (r & 3) + 8 * (r >> 2) + 4 * h;
            pn[(qr << 5) + q] = accB[r];
        }
        if (h == 0) pden[((tileA | 1) << 5) + q] = denB;
    }
}

// ---------------- Kernel 2b: combine halves + W conv + BN stats ----------------
// grid (128 qtiles, 4 batch) x 256 thr.
__global__ __launch_bounds__(256) void attn_combine(
    const float* __restrict__ pnum, const float* __restrict__ pden,
    const float* __restrict__ w_w, const float* __restrict__ w_b,
    float* __restrict__ out2, float* __restrict__ stats1)
{
    __shared__ __align__(16) float obuf[32][36];
    const int tid = threadIdx.x;
    const int b = blockIdx.y, qbase = blockIdx.x << 5;
    const int tile0 = ((b) << 7) | blockIdx.x;          // half 0
    const int tile1 = ((4 + b) << 7) | blockIdx.x;      // half 1

    const float* pn0 = pnum + ((size_t)tile0 << 10);
    const float* pn1 = pnum + ((size_t)tile1 << 10);
#pragma unroll
    for (int k = 0; k < 4; ++k) {
        int e = tid + (k << 8);
        int qr = e >> 5, ci = e & 31;
        float num = pn0[e] + pn1[e];
        float den = pden[(tile0 << 5) + qr] + pden[(tile1 << 5) + qr];
        obuf[qr][ci] = num * (1.0f / den);
    }
    __syncthreads();

    // ---- fused W 1x1 conv over the 32-query tile + BN partial stats ----
    const int qq = tid & 31, cog = tid >> 5;   // 8 co per thread
    float ov[32];
    const float4* orow = (const float4*)&obuf[qq][0];
#pragma unroll
    for (int k4 = 0; k4 < 8; ++k4) {
        float4 t = orow[k4];
        ov[4*k4] = t.x; ov[4*k4+1] = t.y; ov[4*k4+2] = t.z; ov[4*k4+3] = t.w;
    }
    float* dstbase = out2 + (((size_t)(b << 6)) << 12) + qbase + qq;
#pragma unroll
    for (int kk = 0; kk < 8; ++kk) {
        int co = (kk << 3) | cog;
        const float4* wr = (const float4*)&w_w[co << 5];
        float acc2 = w_b[co];
#pragma unroll
        for (int k4 = 0; k4 < 8; ++k4) {
            float4 t = wr[k4];
            acc2 = fmaf(t.x, ov[4*k4],   acc2);
            acc2 = fmaf(t.y, ov[4*k4+1], acc2);
            acc2 = fmaf(t.z, ov[4*k4+2], acc2);
            acc2 = fmaf(t.w, ov[4*k4+3], acc2);
        }
        dstbase[(size_t)co << 12] = acc2;
        // per-co partial sums over the 32 queries (each 32-lane half owns one co)
        float s1 = acc2, s2 = acc2 * acc2;
#pragma unroll
        for (int m = 1; m < 32; m <<= 1) {
            s1 += __shfl_xor(s1, m);
            s2 += __shfl_xor(s2, m);
        }
        if (qq == 0) {
            atomicAdd(&stats1[co << 1], s1);
            atomicAdd(&stats1[(co << 1) | 1], s2);
        }
    }
}

// ---------------- Kernel 3: BN + bilinear 64->128 + residual ----------------
__global__ __launch_bounds__(256) void up_kernel(
    const float* __restrict__ out2, const float* __restrict__ stats1,
    const float* __restrict__ gamma, const float* __restrict__ beta,
    const float* __restrict__ mainf, float* __restrict__ out)
{
    int gid = blockIdx.x * 256 + threadIdx.x;   // < 4*64*128*32
    int j4 = (gid & 31) << 2;
    int i  = (gid >> 5) & 127;
    int co = (gid >> 12) & 63;            // uniform within a block
    int b  = gid >> 18;

    float sm = stats1[co << 1];
    float sq = stats1[(co << 1) | 1];
    float mean = sm * (1.0f / 16384.0f);
    float var  = sq * (1.0f / 16384.0f) - mean * mean;
    float inv  = rsqrtf(var + 1e-5f);
    float scale = gamma[co] * inv;
    float shift = beta[co] - mean * scale;

    int ih = i >> 1;
    int k0, k1; float wi;
    if (i & 1)       { k0 = ih;     k1 = (ih < 63) ? ih + 1 : 63; wi = 0.25f; }
    else if (ih == 0){ k0 = 0;      k1 = 0;                       wi = 0.0f;  }
    else             { k0 = ih - 1; k1 = ih;                      wi = 0.75f; }

    const float* p0r = out2 + ((size_t)((b << 6) | co) << 12) + (k0 << 6);
    const float* p1r = out2 + ((size_t)((b << 6) | co) << 12) + (k1 << 6);

    float res[4];
#pragma unroll
    for (int jj = 0; jj < 4; ++jj) {
        int j = j4 | jj;
        int il = j >> 1;
        int l0, l1; float wj;
        if (j & 1)       { l0 = il;     l1 = (il < 63) ? il + 1 : 63; wj = 0.25f; }
        else if (il == 0){ l0 = 0;      l1 = 0;                       wj = 0.0f;  }
        else             { l0 = il - 1; l1 = il;                      wj = 0.75f; }
        float v00 = p0r[l0], v01 = p0r[l1];
        float v10 = p1r[l0], v11 = p1r[l1];
        float top = v00 + wj * (v01 - v00);
        float bot = v10 + wj * (v11 - v10);
        float v = top + wi * (bot - top);
        res[jj] = fmaf(v, scale, shift);
    }
    size_t idx = (((size_t)((b << 6) | co)) << 14) + (i << 7) + j4;
    float4 m4 = *(const float4*)(mainf + idx);
    *(float4*)(out + idx) = make_float4(res[0] + m4.x, res[1] + m4.y,
                                        res[2] + m4.z, res[3] + m4.w);
}

extern "C" void kernel_launch(void* const* d_in, const int* in_sizes, int n_in,
                              void* d_out, int out_size, void* d_ws, size_t ws_size,
                              hipStream_t stream)
{
    const float* mainf = (const float*)d_in[0];
    const float* cross = (const float*)d_in[1];
    const float* g_w   = (const float*)d_in[2];
    const float* g_b   = (const float*)d_in[3];
    const float* th_w  = (const float*)d_in[4];
    const float* th_b  = (const float*)d_in[5];
    const float* ph_w  = (const float*)d_in[6];
    const float* ph_b  = (const float*)d_in[7];
    const float* w_w   = (const float*)d_in[8];
    const float* w_b   = (const float*)d_in[9];
    const float* gamma = (const float*)d_in[10];
    const float* beta  = (const float*)d_in[11];
    float* out = (float*)d_out;

    __hip_bfloat16* Qb = (__hip_bfloat16*)d_ws;     // 4*4096*32
    __hip_bfloat16* Kb = Qb + 524288;
    __hip_bfloat16* Vt = Kb + 524288;               // [b][ci][4096]
    float* out2   = (float*)(Vt + 524288);          // 4*64*4096
    float* stats1 = out2 + 1048576;                 // 128 used (sum,sumsq per co)
    float* pnum   = stats1 + 512;                   // 1024 tiles x 1024
    float* pden   = pnum + 1048576;                 // 1024 tiles x 32

    qkv_kernel<<<384, 256, 0, stream>>>(cross, mainf, g_w, g_b, th_w, th_b,
                                        ph_w, ph_b, Qb, Kb, Vt, stats1);
    attn_part<<<dim3(64, 4, 2), 256, 0, stream>>>(Qb, Kb, Vt, pnum, pden);
    attn_combine<<<dim3(128, 4), 256, 0, stream>>>(pnum, pden, w_w, w_b, out2, stats1);
    up_kernel<<<4096, 256, 0, stream>>>(out2, stats1, gamma, beta, mainf, out);
}

// Round 6
// 143.944 us; speedup vs baseline: 2.1323x; 2.1323x over previous
//
#include <hip/hip_runtime.h>
#include <hip/hip_bf16.h>

// CrossLocal: B=4, C=64, CI=32, cross 64x64 (Nc=4096), main 128x128.
// R16: atomic-free everywhere (R15 post-mortem: 512-way contended fp32
// atomicAdd to stats1 cost ~175us in EVERY kernel that had it -- R12/R13/R15;
// hierarchical stats_kernel costs ~2us). attn_part keeps R15's 64-q tiles
// (two 32-q tiles share every K/V fragment load -> traffic halved), grid
// (64,4,2)x256. attn_combine = R14's no-atomic version. qkv/stats/up = R10.
// ws: Qb[bf16 1MB] Kb[1MB] Vt[1MB] out2[f32 4MB] stats1[512 f32]
//     pnum[f32 4MB] pden[f32 128KB]

typedef __attribute__((ext_vector_type(8))) short bf16x8;
typedef __attribute__((ext_vector_type(4))) float f32x4;
typedef __attribute__((ext_vector_type(16))) float f32x16;

#define LOG2E 1.4426950408889634f

static __device__ __forceinline__ unsigned short f2bf_bits(float x) {
    __hip_bfloat16 h = __float2bfloat16(x);
    return *(unsigned short*)&h;
}
static __device__ __forceinline__ unsigned int pk2bf(float a, float b) {
    __hip_bfloat162 h = __float22bfloat162_rn(make_float2(a, b));
    return *(unsigned int*)&h;
}

// exp2 all 16 S entries, accumulate denominator, pack to two bf16x8 A-frags.
static __device__ __forceinline__ void softmax_pack(
    const f32x16& s, float& den, bf16x8& ap1, bf16x8& ap2)
{
    float e[16];
#pragma unroll
    for (int r = 0; r < 16; ++r) e[r] = __builtin_amdgcn_exp2f(s[r]);
    den += (((e[0]+e[1])+(e[2]+e[3])) + ((e[4]+e[5])+(e[6]+e[7])))
         + (((e[8]+e[9])+(e[10]+e[11])) + ((e[12]+e[13])+(e[14]+e[15])));
    uint4 t1 = make_uint4(pk2bf(e[0],e[1]), pk2bf(e[2],e[3]),
                          pk2bf(e[4],e[5]), pk2bf(e[6],e[7]));
    uint4 t2 = make_uint4(pk2bf(e[8],e[9]), pk2bf(e[10],e[11]),
                          pk2bf(e[12],e[13]), pk2bf(e[14],e[15]));
    ap1 = *(bf16x8*)&t1; ap2 = *(bf16x8*)&t2;
}

// ---------------- Kernel 1: Q,K,V prep (R9/R10 verbatim) ----------------
__global__ __launch_bounds__(256) void qkv_kernel(
    const float* __restrict__ cross, const float* __restrict__ mainf,
    const float* __restrict__ g_w,  const float* __restrict__ g_b,
    const float* __restrict__ th_w, const float* __restrict__ th_b,
    const float* __restrict__ ph_w, const float* __restrict__ ph_b,
    __hip_bfloat16* __restrict__ Qb, __hip_bfloat16* __restrict__ Kb,
    __hip_bfloat16* __restrict__ Vt)
{
    __shared__ float xs[64][128];            // 32 KB
    const int kind = blockIdx.x >> 7;        // 0=Q,1=K,2=V
    const int sub  = blockIdx.x & 127;
    const int b    = sub >> 5;
    const int n0   = (sub & 31) << 7;        // 128 pixels per block
    const int tid  = threadIdx.x;
    const float* w  = (kind == 0) ? g_w : (kind == 1) ? th_w : ph_w;
    const float* bs = (kind == 0) ? g_b : (kind == 1) ? th_b : ph_b;

    if (kind < 2) {
        const float* src = cross + (((size_t)(b * 64)) << 12) + n0;
        const int jr = (tid & 31) << 2, c0 = tid >> 5;
#pragma unroll
        for (int it = 0; it < 8; ++it) {
            int c = (it << 3) | c0;
            *(float4*)&xs[c][jr] = *(const float4*)(src + ((size_t)c << 12) + jr);
        }
    } else {
        const int px = tid & 127, chh = tid >> 7;
        const int n = n0 + px;
        const int i2 = (n >> 6) << 1, j2 = (n & 63) << 1;
        const float* src = mainf + (((size_t)(b * 64)) << 14) + i2 * 128 + j2;
#pragma unroll 4
        for (int cc = 0; cc < 32; ++cc) {
            int c = (chh << 5) | cc;
            const float2 a = *(const float2*)(src + ((size_t)c << 14));
            const float2 d = *(const float2*)(src + ((size_t)c << 14) + 128);
            xs[c][px] = 0.25f * ((a.x + a.y) + (d.x + d.y));
        }
    }
    __syncthreads();

    const int px = tid & 127, cih = tid >> 7, ci0 = cih << 4;
    float acc[16];
#pragma unroll
    for (int j = 0; j < 16; ++j) acc[j] = bs[ci0 + j];
#pragma unroll 4
    for (int c = 0; c < 64; ++c) {
        float x = xs[c][px];
#pragma unroll
        for (int j = 0; j < 16; ++j)
            acc[j] = fmaf(w[((ci0 + j) << 6) + c], x, acc[j]);
    }
    const int n = n0 + px;
    const int pix = (b << 12) + n;
    if (kind < 2) {
        if (kind == 0) {
#pragma unroll
            for (int j = 0; j < 16; ++j) acc[j] *= LOG2E;
        }
        unsigned int u[8];
#pragma unroll
        for (int i = 0; i < 8; ++i)
            u[i] = (unsigned int)f2bf_bits(acc[2 * i]) |
                   ((unsigned int)f2bf_bits(acc[2 * i + 1]) << 16);
        uint4* d4 = (uint4*)(((kind == 0) ? Qb : Kb) + (size_t)pix * 32 + ci0);
        d4[0] = make_uint4(u[0], u[1], u[2], u[3]);
        d4[1] = make_uint4(u[4], u[5], u[6], u[7]);
    } else {
#pragma unroll
        for (int j = 0; j < 16; ++j)
            Vt[((size_t)((b << 5) | (ci0 + j)) << 12) + n] = __float2bfloat16(acc[j]);
    }
}

// ---------------- Kernel 2: split flash attention, 64-q blocks ----------------
// grid (64 q-pairs, 4 batch, 2 halves) x 256 thr. Wave w owns keys
// [half*2048 + w*512, +512), 16 chunks of 32 keys. Two q-tiles (A=qbase..+31,
// B=+32..63) share every K/V load. Writes pnum[tile][32q][32ci], pden[tile][32q];
// tile = ((half*4+b)<<7) | (blockIdx.x*2+T).
__global__ __launch_bounds__(256) void attn_part(
    const __hip_bfloat16* __restrict__ Qb, const __hip_bfloat16* __restrict__ Kb,
    const __hip_bfloat16* __restrict__ Vt,
    float* __restrict__ pnum, float* __restrict__ pden)
{
    __shared__ __align__(16) float redbuf[3][64][20];
    const int tid = threadIdx.x, lane = tid & 63, w = tid >> 6;
    const int q = lane & 31, h = lane >> 5;
    const int b = blockIdx.y, qbase = blockIdx.x << 6, half = blockIdx.z;
    // sigma: swap bits 2 and 3 of q (K-row permutation)
    const int sig = (q & ~12) | ((q & 4) << 1) | ((q & 8) >> 1);

    // Q B-frags for both tiles: B[k=ci][n=q] -> Qb[qbase(+32)+q][ci=8h.. (+16)]
    const __hip_bfloat16* QrowA = Qb + (((size_t)(b << 12) + qbase + q) << 5);
    const bf16x8 bq1A = *(const bf16x8*)(QrowA + 8 * h);
    const bf16x8 bq2A = *(const bf16x8*)(QrowA + 16 + 8 * h);
    const __hip_bfloat16* QrowB = QrowA + (32 << 5);
    const bf16x8 bq1B = *(const bf16x8*)(QrowB + 8 * h);
    const bf16x8 bq2B = *(const bf16x8*)(QrowB + 16 + 8 * h);

    const __hip_bfloat16* Kbb = Kb + ((size_t)(b << 12) << 5);
    const __hip_bfloat16* Vbb = Vt + ((size_t)(b << 5) << 12) + ((size_t)q << 12);
    const int kq = (half << 11) + (w << 9);
#define LDK1(k) (*(const bf16x8*)(Kbb + ((size_t)((k) + sig) << 5) + 8 * h))
#define LDK2(k) (*(const bf16x8*)(Kbb + ((size_t)((k) + sig) << 5) + 16 + 8 * h))
#define LDV1(k) (*(const bf16x8*)(Vbb + (k) + 8 * h))
#define LDV2(k) (*(const bf16x8*)(Vbb + (k) + 16 + 8 * h))

    f32x16 accA, accB;
#pragma unroll
    for (int r = 0; r < 16; ++r) { accA[r] = 0.f; accB[r] = 0.f; }
    const f32x16 z16 = accA;
    float denA = 0.f, denB = 0.f;

    bf16x8 a1c = LDK1(kq),      a2c = LDK2(kq);
    bf16x8 vb1 = LDV1(kq),      vb2 = LDV2(kq);
    bf16x8 a1n = LDK1(kq + 32), a2n = LDK2(kq + 32);
    bf16x8 vn1 = LDV1(kq + 32), vn2 = LDV2(kq + 32);
    bf16x8 apA1, apA2, apB1, apB2, vp1, vp2;

    // ---- chunk 0: S phase only, both tiles ----
    {
        f32x16 sA = __builtin_amdgcn_mfma_f32_32x32x16_bf16(a1c, bq1A, z16, 0, 0, 0);
        sA = __builtin_amdgcn_mfma_f32_32x32x16_bf16(a2c, bq2A, sA, 0, 0, 0);
        f32x16 sB = __builtin_amdgcn_mfma_f32_32x32x16_bf16(a1c, bq1B, z16, 0, 0, 0);
        sB = __builtin_amdgcn_mfma_f32_32x32x16_bf16(a2c, bq2B, sB, 0, 0, 0);
        softmax_pack(sA, denA, apA1, apA2);
        softmax_pack(sB, denB, apB1, apB2);
    }

#pragma unroll 2
    for (int ch = 1; ch < 16; ++ch) {
        const int kn = kq + ((ch + 1) & 15) * 32;   // last iter wraps in-range
        vp1 = vb1; vp2 = vb2;          // V(ch-1) for this iter's PV
        vb1 = vn1; vb2 = vn2;          // V(ch)
        a1c = a1n; a2c = a2n;          // K(ch)
        a1n = LDK1(kn); a2n = LDK2(kn);
        vn1 = LDV1(kn); vn2 = LDV2(kn);

        // S of chunk ch, both tiles (shared K frags)
        f32x16 sA = __builtin_amdgcn_mfma_f32_32x32x16_bf16(a1c, bq1A, z16, 0, 0, 0);
        sA = __builtin_amdgcn_mfma_f32_32x32x16_bf16(a2c, bq2A, sA, 0, 0, 0);
        f32x16 sB = __builtin_amdgcn_mfma_f32_32x32x16_bf16(a1c, bq1B, z16, 0, 0, 0);
        sB = __builtin_amdgcn_mfma_f32_32x32x16_bf16(a2c, bq2B, sB, 0, 0, 0);

        // PV of chunk ch-1 (ap packed last iteration, shared V frags)
        accA = __builtin_amdgcn_mfma_f32_32x32x16_bf16(apA1, vp1, accA, 0, 0, 0);
        accA = __builtin_amdgcn_mfma_f32_32x32x16_bf16(apA2, vp2, accA, 0, 0, 0);
        accB = __builtin_amdgcn_mfma_f32_32x32x16_bf16(apB1, vp1, accB, 0, 0, 0);
        accB = __builtin_amdgcn_mfma_f32_32x32x16_bf16(apB2, vp2, accB, 0, 0, 0);

        softmax_pack(sA, denA, apA1, apA2);
        softmax_pack(sB, denB, apB1, apB2);
    }
    // tail: PV of chunk 15 (V(15) sits in vb1/vb2 after last rotation)
    accA = __builtin_amdgcn_mfma_f32_32x32x16_bf16(apA1, vb1, accA, 0, 0, 0);
    accA = __builtin_amdgcn_mfma_f32_32x32x16_bf16(apA2, vb2, accA, 0, 0, 0);
    accB = __builtin_amdgcn_mfma_f32_32x32x16_bf16(apB1, vb1, accB, 0, 0, 0);
    accB = __builtin_amdgcn_mfma_f32_32x32x16_bf16(apB2, vb2, accB, 0, 0, 0);
#undef LDK1
#undef LDK2
#undef LDV1
#undef LDV2

    // den(lane) covers query q over this lane's 16 keys/chunk; other half:
    denA += __shfl_xor(denA, 32);
    denB += __shfl_xor(denB, 32);

    const int tileA = (((half << 2) | b) << 7) | (blockIdx.x << 1);

    // ---- tile A cross-wave combine + partial write ----
    if (w) {
        float* rb = &redbuf[w - 1][lane][0];
        f32x4* rb4 = (f32x4*)rb;
#pragma unroll
        for (int p = 0; p < 4; ++p) {
            f32x4 t = {accA[4*p], accA[4*p+1], accA[4*p+2], accA[4*p+3]};
            rb4[p] = t;
        }
        rb[16] = denA;
    }
    __syncthreads();
    if (w == 0) {
#pragma unroll
        for (int ww = 0; ww < 3; ++ww) {
            const float* rb = &redbuf[ww][lane][0];
            const f32x4* rb4 = (const f32x4*)rb;
#pragma unroll
            for (int p = 0; p < 4; ++p) {
                f32x4 t = rb4[p];
                accA[4*p] += t[0]; accA[4*p+1] += t[1];
                accA[4*p+2] += t[2]; accA[4*p+3] += t[3];
            }
            denA += rb[16];
        }
        // O^T C-layout: row(query)=(r&3)+8*(r>>2)+4h, col(ci)=q
        float* pn = pnum + ((size_t)tileA << 10);
#pragma unroll
        for (int r = 0; r < 16; ++r) {
            int qr = (r & 3) + 8 * (r >> 2) + 4 * h;
            pn[(qr << 5) + q] = accA[r];
        }
        if (h == 0) pden[(tileA << 5) + q] = denA;
    }
    __syncthreads();

    // ---- tile B cross-wave combine + partial write ----
    if (w) {
        float* rb = &redbuf[w - 1][lane][0];
        f32x4* rb4 = (f32x4*)rb;
#pragma unroll
        for (int p = 0; p < 4; ++p) {
            f32x4 t = {accB[4*p], accB[4*p+1], accB[4*p+2], accB[4*p+3]};
            rb4[p] = t;
        }
        rb[16] = denB;
    }
    __syncthreads();
    if (w == 0) {
#pragma unroll
        for (int ww = 0; ww < 3; ++ww) {
            const float* rb = &redbuf[ww][lane][0];
            const f32x4* rb4 = (const f32x4*)rb;
#pragma unroll
            for (int p = 0; p < 4; ++p) {
                f32x4 t = rb4[p];
                accB[4*p] += t[0]; accB[4*p+1] += t[1];
                accB[4*p+2] += t[2]; accB[4*p+3] += t[3];
            }
            denB += rb[16];
        }
        float* pn = pnum + ((size_t)(tileA | 1) << 10);
#pragma unroll
        for (int r = 0; r < 16; ++r) {
            int qr = (r & 3) + 8 * (r >> 2) + 4 * h;
            pn[(qr << 5) + q] = accB[r];
        }
        if (h == 0) pden[((tileA | 1) << 5) + q] = denB;
    }
}

// ---------------- Kernel 2b: combine halves + W 1x1 conv (no atomics) ----------
// grid (128 qtiles, 4 batch) x 256 thr.
__global__ __launch_bounds__(256) void attn_combine(
    const float* __restrict__ pnum, const float* __restrict__ pden,
    const float* __restrict__ w_w, const float* __restrict__ w_b,
    float* __restrict__ out2)
{
    __shared__ __align__(16) float obuf[32][36];
    const int tid = threadIdx.x;
    const int b = blockIdx.y, qbase = blockIdx.x << 5;
    const int tile0 = ((b) << 7) | blockIdx.x;          // half 0
    const int tile1 = ((4 + b) << 7) | blockIdx.x;      // half 1

    const float* pn0 = pnum + ((size_t)tile0 << 10);
    const float* pn1 = pnum + ((size_t)tile1 << 10);
#pragma unroll
    for (int k = 0; k < 4; ++k) {
        int e = tid + (k << 8);
        int qr = e >> 5, ci = e & 31;
        float num = pn0[e] + pn1[e];
        float den = pden[(tile0 << 5) + qr] + pden[(tile1 << 5) + qr];
        obuf[qr][ci] = num * (1.0f / den);
    }
    __syncthreads();

    // ---- fused W 1x1 conv over the 32-query tile (R10 verbatim) ----
    const int qq = tid & 31, cog = tid >> 5;   // 8 co per thread
    float ov[32];
    const float4* orow = (const float4*)&obuf[qq][0];
#pragma unroll
    for (int k4 = 0; k4 < 8; ++k4) {
        float4 t = orow[k4];
        ov[4*k4] = t.x; ov[4*k4+1] = t.y; ov[4*k4+2] = t.z; ov[4*k4+3] = t.w;
    }
    float* dstbase = out2 + (((size_t)(b << 6)) << 12) + qbase + qq;
#pragma unroll
    for (int kk = 0; kk < 8; ++kk) {
        int co = (kk << 3) | cog;
        const float4* wr = (const float4*)&w_w[co << 5];
        float acc2 = w_b[co];
#pragma unroll
        for (int k4 = 0; k4 < 8; ++k4) {
            float4 t = wr[k4];
            acc2 = fmaf(t.x, ov[4*k4],   acc2);
            acc2 = fmaf(t.y, ov[4*k4+1], acc2);
            acc2 = fmaf(t.z, ov[4*k4+2], acc2);
            acc2 = fmaf(t.w, ov[4*k4+3], acc2);
        }
        dstbase[(size_t)co << 12] = acc2;
    }
}

// ---------------- Kernel 3: BN partial statistics (R9/R10 verbatim) ----------------
__global__ __launch_bounds__(256) void stats_kernel(
    const float* __restrict__ out2, float* __restrict__ stats1)
{
    int co = blockIdx.x >> 2, b = blockIdx.x & 3, t = threadIdx.x;
    const float* p = out2 + ((size_t)((b << 6) | co) << 12);
    float s = 0.f, s2 = 0.f;
#pragma unroll
    for (int ii = 0; ii < 16; ++ii) {
        float v = p[(ii << 8) | t];
        s += v; s2 = fmaf(v, v, s2);
    }
    __shared__ float rs[256], rs2[256];
    rs[t] = s; rs2[t] = s2;
    __syncthreads();
    for (int off = 128; off > 0; off >>= 1) {
        if (t < off) { rs[t] += rs[t + off]; rs2[t] += rs2[t + off]; }
        __syncthreads();
    }
    if (t == 0) {
        stats1[blockIdx.x * 2]     = rs[0];
        stats1[blockIdx.x * 2 + 1] = rs2[0];
    }
}

// ---------------- Kernel 4: BN + bilinear 64->128 + residual (R9/R10 verbatim) ----
__global__ __launch_bounds__(256) void up_kernel(
    const float* __restrict__ out2, const float* __restrict__ stats1,
    const float* __restrict__ gamma, const float* __restrict__ beta,
    const float* __restrict__ mainf, float* __restrict__ out)
{
    int gid = blockIdx.x * 256 + threadIdx.x;   // < 4*64*128*32
    int j4 = (gid & 31) << 2;
    int i  = (gid >> 5) & 127;
    int co = (gid >> 12) & 63;            // uniform within a block
    int b  = gid >> 18;

    float sm = 0.f, sq = 0.f;
#pragma unroll
    for (int bb = 0; bb < 4; ++bb) {
        sm += stats1[((co << 2) | bb) * 2];
        sq += stats1[((co << 2) | bb) * 2 + 1];
    }
    float mean = sm * (1.0f / 16384.0f);
    float var  = sq * (1.0f / 16384.0f) - mean * mean;
    float inv  = rsqrtf(var + 1e-5f);
    float scale = gamma[co] * inv;
    float shift = beta[co] - mean * scale;

    int ih = i >> 1;
    int k0, k1; float wi;
    if (i & 1)       { k0 = ih;     k1 = (ih < 63) ? ih + 1 : 63; wi = 0.25f; }
    else if (ih == 0){ k0 = 0;      k1 = 0;                       wi = 0.0f;  }
    else             { k0 = ih - 1; k1 = ih;                      wi = 0.75f; }

    const float* p0r = out2 + ((size_t)((b << 6) | co) << 12) + (k0 << 6);
    const float* p1r = out2 + ((size_t)((b << 6) | co) << 12) + (k1 << 6);

    float res[4];
#pragma unroll
    for (int jj = 0; jj < 4; ++jj) {
        int j = j4 | jj;
        int il = j >> 1;
        int l0, l1; float wj;
        if (j & 1)       { l0 = il;     l1 = (il < 63) ? il + 1 : 63; wj = 0.25f; }
        else if (il == 0){ l0 = 0;      l1 = 0;                       wj = 0.0f;  }
        else             { l0 = il - 1; l1 = il;                      wj = 0.75f; }
        float v00 = p0r[l0], v01 = p0r[l1];
        float v10 = p1r[l0], v11 = p1r[l1];
        float top = v00 + wj * (v01 - v00);
        float bot = v10 + wj * (v11 - v10);
        float v = top + wi * (bot - top);
        res[jj] = fmaf(v, scale, shift);
    }
    size_t idx = (((size_t)((b << 6) | co)) << 14) + (i << 7) + j4;
    float4 m4 = *(const float4*)(mainf + idx);
    *(float4*)(out + idx) = make_float4(res[0] + m4.x, res[1] + m4.y,
                                        res[2] + m4.z, res[3] + m4.w);
}

extern "C" void kernel_launch(void* const* d_in, const int* in_sizes, int n_in,
                              void* d_out, int out_size, void* d_ws, size_t ws_size,
                              hipStream_t stream)
{
    const float* mainf = (const float*)d_in[0];
    const float* cross = (const float*)d_in[1];
    const float* g_w   = (const float*)d_in[2];
    const float* g_b   = (const float*)d_in[3];
    const float* th_w  = (const float*)d_in[4];
    const float* th_b  = (const float*)d_in[5];
    const float* ph_w  = (const float*)d_in[6];
    const float* ph_b  = (const float*)d_in[7];
    const float* w_w   = (const float*)d_in[8];
    const float* w_b   = (const float*)d_in[9];
    const float* gamma = (const float*)d_in[10];
    const float* beta  = (const float*)d_in[11];
    float* out = (float*)d_out;

    __hip_bfloat16* Qb = (__hip_bfloat16*)d_ws;     // 4*4096*32
    __hip_bfloat16* Kb = Qb + 524288;
    __hip_bfloat16* Vt = Kb + 524288;               // [b][ci][4096]
    float* out2   = (float*)(Vt + 524288);          // 4*64*4096
    float* stats1 = out2 + 1048576;                 // 512
    float* pnum   = stats1 + 512;                   // 1024 tiles x 1024
    float* pden   = pnum + 1048576;                 // 1024 tiles x 32

    qkv_kernel<<<384, 256, 0, stream>>>(cross, mainf, g_w, g_b, th_w, th_b,
                                        ph_w, ph_b, Qb, Kb, Vt);
    attn_part<<<dim3(64, 4, 2), 256, 0, stream>>>(Qb, Kb, Vt, pnum, pden);
    attn_combine<<<dim3(128, 4), 256, 0, stream>>>(pnum, pden, w_w, w_b, out2);
    stats_kernel<<<256, 256, 0, stream>>>(out2, stats1);
    up_kernel<<<4096, 256, 0, stream>>>(out2, stats1, gamma, beta, mainf, out);
}